// Round 2
// baseline (384.414 us; speedup 1.0000x reference)
//
#include <hip/hip_runtime.h>
#include <hip/hip_bf16.h>

#define BN 4
#define NN 4096
#define DD 128

typedef __attribute__((ext_vector_type(8))) __bf16 bf16x8;
typedef __attribute__((ext_vector_type(4))) float f32x4;

__device__ inline unsigned short f2bf(float f) {
  unsigned int u = __float_as_uint(f);
  unsigned int r = (u + 0x7FFFu + ((u >> 16) & 1u)) >> 16;
  return (unsigned short)r;
}
__device__ inline float bf2f(unsigned short s) {
  return __uint_as_float(((unsigned int)s) << 16);
}

// ---------------- kernel 1: cast x (fp32) -> xb (bf16) ----------------
__global__ __launch_bounds__(256) void k_cvt(const float* __restrict__ x,
                                             unsigned short* __restrict__ xb) {
  int i = (blockIdx.x * 256 + threadIdx.x) * 8;
  float4 a = *(const float4*)(x + i);
  float4 c = *(const float4*)(x + i + 4);
  alignas(16) unsigned short r[8] = {f2bf(a.x), f2bf(a.y), f2bf(a.z), f2bf(a.w),
                                     f2bf(c.x), f2bf(c.y), f2bf(c.z), f2bf(c.w)};
  *(uint4*)(xb + i) = *(const uint4*)r;
}

// ---------------- kernel 2: colsum[b][j] = sum_i relu(<x_i,x_j>) ----------------
__global__ __launch_bounds__(256) void k_colsum(const unsigned short* __restrict__ xb,
                                                float* __restrict__ colsum) {
  __shared__ unsigned short Xj[64 * 128];
  __shared__ unsigned short Xi[64 * 128];
  __shared__ float red[2][64];
  const int b = blockIdx.y, j0 = blockIdx.x * 64;
  const int tid = threadIdx.x, lane = tid & 63, w = tid >> 6;
  const unsigned short* xbb = xb + b * NN * DD;

  // 64 rows x 16 granules (8 ushort each) = full 128-wide tile
  for (int c = tid; c < 1024; c += 256) {
    int row = c >> 4, g = c & 15;
    *(uint4*)&Xj[row * 128 + ((g ^ (row & 7)) << 3)] =
        *(const uint4*)&xbb[(j0 + row) * 128 + g * 8];
  }
  const int wr = w >> 1, wc = w & 1;
  float colacc0 = 0.f, colacc1 = 0.f;

  for (int i0 = 0; i0 < NN; i0 += 64) {
    __syncthreads();
    for (int c = tid; c < 1024; c += 256) {
      int row = c >> 4, g = c & 15;
      *(uint4*)&Xi[row * 128 + ((g ^ (row & 7)) << 3)] =
          *(const uint4*)&xbb[(i0 + row) * 128 + g * 8];
    }
    __syncthreads();

    f32x4 acc00 = {}, acc01 = {}, acc10 = {}, acc11 = {};
#pragma unroll
    for (int kk = 0; kk < 4; ++kk) {
      int g = kk * 4 + (lane >> 4);
      bf16x8 a0, a1, b0, b1;
      { int r = wr * 32 + (lane & 15);      a0 = *(const bf16x8*)&Xi[r * 128 + ((g ^ (r & 7)) << 3)]; }
      { int r = wr * 32 + 16 + (lane & 15); a1 = *(const bf16x8*)&Xi[r * 128 + ((g ^ (r & 7)) << 3)]; }
      { int r = wc * 32 + (lane & 15);      b0 = *(const bf16x8*)&Xj[r * 128 + ((g ^ (r & 7)) << 3)]; }
      { int r = wc * 32 + 16 + (lane & 15); b1 = *(const bf16x8*)&Xj[r * 128 + ((g ^ (r & 7)) << 3)]; }
      acc00 = __builtin_amdgcn_mfma_f32_16x16x32_bf16(a0, b0, acc00, 0, 0, 0);
      acc01 = __builtin_amdgcn_mfma_f32_16x16x32_bf16(a0, b1, acc01, 0, 0, 0);
      acc10 = __builtin_amdgcn_mfma_f32_16x16x32_bf16(a1, b0, acc10, 0, 0, 0);
      acc11 = __builtin_amdgcn_mfma_f32_16x16x32_bf16(a1, b1, acc11, 0, 0, 0);
    }
    // column sums of relu(S): C layout col = lane&15, rows summed out
    {
      float s0 = 0.f, s1 = 0.f;
#pragma unroll
      for (int r = 0; r < 4; ++r) {
        s0 += fmaxf(acc00[r], 0.f) + fmaxf(acc10[r], 0.f);
        s1 += fmaxf(acc01[r], 0.f) + fmaxf(acc11[r], 0.f);
      }
      s0 += __shfl_xor(s0, 16); s0 += __shfl_xor(s0, 32);
      s1 += __shfl_xor(s1, 16); s1 += __shfl_xor(s1, 32);
      colacc0 += s0; colacc1 += s1;
    }
  }
  __syncthreads();
  if (lane < 16) {
    red[wr][wc * 32 + lane] = colacc0;
    red[wr][wc * 32 + 16 + lane] = colacc1;
  }
  __syncthreads();
  if (tid < 64) colsum[b * NN + j0 + tid] = red[0][tid] + red[1][tid];
}

// ---------------- kernel 3: yt[b][d][j] = bf16(x[b][j][d] / colsum[b][j]) ----------------
__global__ __launch_bounds__(256) void k_ytrans(const float* __restrict__ x,
                                                const float* __restrict__ colsum,
                                                unsigned short* __restrict__ yt) {
  __shared__ unsigned short T[64 * 72];
  const int b = blockIdx.z, j0 = blockIdx.y * 64, d0 = blockIdx.x * 64;
  const int tid = threadIdx.x;
  int jr = tid >> 2, q0 = (tid & 3) * 16;
  float inv = 1.0f / colsum[b * NN + j0 + jr];
  const float* xr = x + (size_t)(b * NN + j0 + jr) * DD + d0 + q0;
#pragma unroll
  for (int q = 0; q < 4; ++q) {
    float4 v = *(const float4*)(xr + q * 4);
    int dc = q0 + q * 4;
    T[jr * 72 + dc + 0] = f2bf(v.x * inv);
    T[jr * 72 + dc + 1] = f2bf(v.y * inv);
    T[jr * 72 + dc + 2] = f2bf(v.z * inv);
    T[jr * 72 + dc + 3] = f2bf(v.w * inv);
  }
  __syncthreads();
  for (int c = tid; c < 512; c += 256) {
    int dr = c >> 3, jg = c & 7;
    alignas(16) unsigned short tmp[8];
#pragma unroll
    for (int u = 0; u < 8; ++u) tmp[u] = T[(jg * 8 + u) * 72 + dr];
    *(uint4*)&yt[(size_t)(b * DD + d0 + dr) * NN + j0 + jg * 8] = *(const uint4*)tmp;
  }
}

// ---------------- kernel 4: pre[b][i][:] = sum_j relu(<x_i,x_j>) * y[j][:] ----------------
__global__ __launch_bounds__(256) void k_pass2(const unsigned short* __restrict__ xb,
                                               const unsigned short* __restrict__ yt,
                                               unsigned short* __restrict__ pre) {
  __shared__ unsigned short Xi[64 * 128];
  __shared__ unsigned short Xj[64 * 128];
  __shared__ unsigned short Ys[128 * 64];
  __shared__ unsigned short P[64 * 64];
  const int b = blockIdx.y, i0 = blockIdx.x * 64;
  const int tid = threadIdx.x, lane = tid & 63, w = tid >> 6;
  const unsigned short* xbb = xb + b * NN * DD;
  const unsigned short* ytb = yt + (size_t)b * DD * NN;

  for (int c = tid; c < 1024; c += 256) {
    int row = c >> 4, g = c & 15;
    *(uint4*)&Xi[row * 128 + ((g ^ (row & 7)) << 3)] =
        *(const uint4*)&xbb[(i0 + row) * 128 + g * 8];
  }
  const int wr = w >> 1, wc = w & 1;
  f32x4 oacc[8] = {};

  for (int j0 = 0; j0 < NN; j0 += 64) {
    __syncthreads();
    for (int c = tid; c < 2048; c += 256) {
      if (c < 1024) {
        int row = c >> 4, g = c & 15;
        *(uint4*)&Xj[row * 128 + ((g ^ (row & 7)) << 3)] =
            *(const uint4*)&xbb[(j0 + row) * 128 + g * 8];
      } else {
        int cc = c - 1024;
        int dr = cc >> 3, jg = cc & 7;
        *(uint4*)&Ys[dr * 64 + ((jg ^ (dr & 7)) << 3)] =
            *(const uint4*)&ytb[(size_t)dr * NN + j0 + jg * 8];
      }
    }
    __syncthreads();

    f32x4 acc00 = {}, acc01 = {}, acc10 = {}, acc11 = {};
#pragma unroll
    for (int kk = 0; kk < 4; ++kk) {
      int g = kk * 4 + (lane >> 4);
      bf16x8 a0, a1, b0, b1;
      { int r = wr * 32 + (lane & 15);      a0 = *(const bf16x8*)&Xi[r * 128 + ((g ^ (r & 7)) << 3)]; }
      { int r = wr * 32 + 16 + (lane & 15); a1 = *(const bf16x8*)&Xi[r * 128 + ((g ^ (r & 7)) << 3)]; }
      { int r = wc * 32 + (lane & 15);      b0 = *(const bf16x8*)&Xj[r * 128 + ((g ^ (r & 7)) << 3)]; }
      { int r = wc * 32 + 16 + (lane & 15); b1 = *(const bf16x8*)&Xj[r * 128 + ((g ^ (r & 7)) << 3)]; }
      acc00 = __builtin_amdgcn_mfma_f32_16x16x32_bf16(a0, b0, acc00, 0, 0, 0);
      acc01 = __builtin_amdgcn_mfma_f32_16x16x32_bf16(a0, b1, acc01, 0, 0, 0);
      acc10 = __builtin_amdgcn_mfma_f32_16x16x32_bf16(a1, b0, acc10, 0, 0, 0);
      acc11 = __builtin_amdgcn_mfma_f32_16x16x32_bf16(a1, b1, acc11, 0, 0, 0);
    }
    // relu -> P (bf16, swizzled), exact C layout
#pragma unroll
    for (int m = 0; m < 2; ++m)
#pragma unroll
      for (int n = 0; n < 2; ++n)
#pragma unroll
        for (int r = 0; r < 4; ++r) {
          float v;
          if (m == 0 && n == 0) v = acc00[r];
          else if (m == 0 && n == 1) v = acc01[r];
          else if (m == 1 && n == 0) v = acc10[r];
          else v = acc11[r];
          int row = wr * 32 + m * 16 + (lane >> 4) * 4 + r;
          int col = wc * 32 + n * 16 + (lane & 15);
          P[row * 64 + (((col >> 3) ^ (row & 7)) << 3) + (col & 7)] = f2bf(fmaxf(v, 0.f));
        }
    __syncthreads();
    // out += P @ Y   (wave w owns rows w*16 .. w*16+15, all 128 d columns)
#pragma unroll
    for (int kq = 0; kq < 2; ++kq) {
      int g = kq * 4 + (lane >> 4);
      bf16x8 a;
      { int r = w * 16 + (lane & 15); a = *(const bf16x8*)&P[r * 64 + ((g ^ (r & 7)) << 3)]; }
#pragma unroll
      for (int n = 0; n < 8; ++n) {
        int r = n * 16 + (lane & 15);
        bf16x8 bb = *(const bf16x8*)&Ys[r * 64 + ((g ^ (r & 7)) << 3)];
        oacc[n] = __builtin_amdgcn_mfma_f32_16x16x32_bf16(a, bb, oacc[n], 0, 0, 0);
      }
    }
  }
  // epilogue: oacc (fp32) -> bf16, via LDS (Xi reused, linear) for coalesced stores
  __syncthreads();
#pragma unroll
  for (int n = 0; n < 8; ++n)
#pragma unroll
    for (int r = 0; r < 4; ++r) {
      int row = w * 16 + (lane >> 4) * 4 + r;
      int col = n * 16 + (lane & 15);
      Xi[row * 128 + col] = f2bf(oacc[n][r]);
    }
  __syncthreads();
  for (int c = tid; c < 1024; c += 256) {
    int row = c >> 4, g = c & 15;
    *(uint4*)&pre[(size_t)(b * NN + i0 + row) * DD + g * 8] = *(const uint4*)&Xi[row * 128 + g * 8];
  }
}

// ---------------- kernel 5: out = tanh(pre @ W^T + bias) + x ----------------
__global__ __launch_bounds__(256) void k_final(const unsigned short* __restrict__ pre,
                                               const float* __restrict__ W,
                                               const float* __restrict__ bias,
                                               const float* __restrict__ x,
                                               float* __restrict__ out) {
  __shared__ float Wt[128 * 128];  // Wt[d][h] = W[h][d]
  const int tid = threadIdx.x;
  const int r0 = blockIdx.x * 64;
  {
    int h = tid >> 1, k0 = (tid & 1) * 64;
    const float* wr = W + h * 128 + k0;
#pragma unroll
    for (int q = 0; q < 16; ++q) {
      float4 v = *(const float4*)(wr + q * 4);
      Wt[(k0 + q * 4 + 0) * 128 + h] = v.x;
      Wt[(k0 + q * 4 + 1) * 128 + h] = v.y;
      Wt[(k0 + q * 4 + 2) * 128 + h] = v.z;
      Wt[(k0 + q * 4 + 3) * 128 + h] = v.w;
    }
  }
  const int h = tid & 127;
  float bh = bias[h];
  __syncthreads();
  for (int it = 0; it < 32; ++it) {
    int ri = r0 + it * 2 + (tid >> 7);
    const unsigned short* pr = pre + (size_t)ri * 128;
    float acc = bh;
#pragma unroll
    for (int k8 = 0; k8 < 16; ++k8) {
      uint4 pk = *(const uint4*)(pr + k8 * 8);
      alignas(16) unsigned short us[8];
      *(uint4*)us = pk;
#pragma unroll
      for (int u = 0; u < 8; ++u) acc += bf2f(us[u]) * Wt[(k8 * 8 + u) * 128 + h];
    }
    out[(size_t)ri * 128 + h] = tanhf(acc) + x[(size_t)ri * 128 + h];
  }
}

extern "C" void kernel_launch(void* const* d_in, const int* in_sizes, int n_in,
                              void* d_out, int out_size, void* d_ws, size_t ws_size,
                              hipStream_t stream) {
  (void)in_sizes; (void)n_in; (void)out_size; (void)ws_size;
  const float* x = (const float*)d_in[0];
  const float* W = (const float*)d_in[1];
  const float* bias = (const float*)d_in[2];
  float* out = (float*)d_out;
  char* ws = (char*)d_ws;
  unsigned short* xb = (unsigned short*)ws;                          // 4 MB
  unsigned short* yt = (unsigned short*)(ws + (4u << 20));           // 4 MB
  float* colsum = (float*)(ws + (8u << 20));                         // 64 KB
  unsigned short* pre = (unsigned short*)(ws + (8u << 20) + (1u << 16));  // 4 MB

  k_cvt<<<1024, 256, 0, stream>>>(x, xb);
  k_colsum<<<dim3(64, 4), 256, 0, stream>>>(xb, colsum);
  k_ytrans<<<dim3(2, 64, 4), 256, 0, stream>>>(x, colsum, yt);
  k_pass2<<<dim3(64, 4), 256, 0, stream>>>(xb, yt, pre);
  k_final<<<256, 256, 0, stream>>>(pre, W, bias, x, out);
}

// Round 3
// 216.456 us; speedup vs baseline: 1.7759x; 1.7759x over previous
//
#include <hip/hip_runtime.h>
#include <hip/hip_bf16.h>

#define BN 4
#define NN 4096
#define DD 128

typedef __attribute__((ext_vector_type(8))) __bf16 bf16x8;
typedef __attribute__((ext_vector_type(4))) float f32x4;

__device__ inline unsigned short f2bf(float f) {
  unsigned int u = __float_as_uint(f);
  unsigned int r = (u + 0x7FFFu + ((u >> 16) & 1u)) >> 16;
  return (unsigned short)r;
}
__device__ inline float bf2f(unsigned short s) {
  return __uint_as_float(((unsigned int)s) << 16);
}

// ---------------- kernel 1: cast x (fp32) -> xb (bf16) ----------------
__global__ __launch_bounds__(256) void k_cvt(const float* __restrict__ x,
                                             unsigned short* __restrict__ xb) {
  int i = (blockIdx.x * 256 + threadIdx.x) * 8;
  float4 a = *(const float4*)(x + i);
  float4 c = *(const float4*)(x + i + 4);
  alignas(16) unsigned short r[8] = {f2bf(a.x), f2bf(a.y), f2bf(a.z), f2bf(a.w),
                                     f2bf(c.x), f2bf(c.y), f2bf(c.z), f2bf(c.w)};
  *(uint4*)(xb + i) = *(const uint4*)r;
}

// ---- kernel 2: colpart[(ic*BN+b)][j] = sum_{i in chunk ic} relu(<x_i,x_j>) ----
__global__ __launch_bounds__(256) void k_colsum(const unsigned short* __restrict__ xb,
                                                float* __restrict__ colpart) {
  __shared__ unsigned short Xj[64 * 128];
  __shared__ unsigned short Xi[64 * 128];
  __shared__ float red[2][64];
  const int b = blockIdx.y, j0 = blockIdx.x * 64, ic = blockIdx.z;
  const int tid = threadIdx.x, lane = tid & 63, w = tid >> 6;
  const unsigned short* xbb = xb + b * NN * DD;

  // 64 rows x 16 granules (8 ushort each) = full 128-wide tile
  for (int c = tid; c < 1024; c += 256) {
    int row = c >> 4, g = c & 15;
    *(uint4*)&Xj[row * 128 + ((g ^ (row & 7)) << 3)] =
        *(const uint4*)&xbb[(j0 + row) * 128 + g * 8];
  }
  const int wr = w >> 1, wc = w & 1;
  float colacc0 = 0.f, colacc1 = 0.f;

  const int ibeg = ic * (NN / 8), iend = ibeg + (NN / 8);
  for (int i0 = ibeg; i0 < iend; i0 += 64) {
    __syncthreads();
    for (int c = tid; c < 1024; c += 256) {
      int row = c >> 4, g = c & 15;
      *(uint4*)&Xi[row * 128 + ((g ^ (row & 7)) << 3)] =
          *(const uint4*)&xbb[(i0 + row) * 128 + g * 8];
    }
    __syncthreads();

    f32x4 acc00 = {}, acc01 = {}, acc10 = {}, acc11 = {};
#pragma unroll
    for (int kk = 0; kk < 4; ++kk) {
      int g = kk * 4 + (lane >> 4);
      bf16x8 a0, a1, b0, b1;
      { int r = wr * 32 + (lane & 15);      a0 = *(const bf16x8*)&Xi[r * 128 + ((g ^ (r & 7)) << 3)]; }
      { int r = wr * 32 + 16 + (lane & 15); a1 = *(const bf16x8*)&Xi[r * 128 + ((g ^ (r & 7)) << 3)]; }
      { int r = wc * 32 + (lane & 15);      b0 = *(const bf16x8*)&Xj[r * 128 + ((g ^ (r & 7)) << 3)]; }
      { int r = wc * 32 + 16 + (lane & 15); b1 = *(const bf16x8*)&Xj[r * 128 + ((g ^ (r & 7)) << 3)]; }
      acc00 = __builtin_amdgcn_mfma_f32_16x16x32_bf16(a0, b0, acc00, 0, 0, 0);
      acc01 = __builtin_amdgcn_mfma_f32_16x16x32_bf16(a0, b1, acc01, 0, 0, 0);
      acc10 = __builtin_amdgcn_mfma_f32_16x16x32_bf16(a1, b0, acc10, 0, 0, 0);
      acc11 = __builtin_amdgcn_mfma_f32_16x16x32_bf16(a1, b1, acc11, 0, 0, 0);
    }
    {
      float s0 = 0.f, s1 = 0.f;
#pragma unroll
      for (int r = 0; r < 4; ++r) {
        s0 += fmaxf(acc00[r], 0.f) + fmaxf(acc10[r], 0.f);
        s1 += fmaxf(acc01[r], 0.f) + fmaxf(acc11[r], 0.f);
      }
      s0 += __shfl_xor(s0, 16); s0 += __shfl_xor(s0, 32);
      s1 += __shfl_xor(s1, 16); s1 += __shfl_xor(s1, 32);
      colacc0 += s0; colacc1 += s1;
    }
  }
  __syncthreads();
  if (lane < 16) {
    red[wr][wc * 32 + lane] = colacc0;
    red[wr][wc * 32 + 16 + lane] = colacc1;
  }
  __syncthreads();
  if (tid < 64) colpart[(ic * BN + b) * NN + j0 + tid] = red[0][tid] + red[1][tid];
}

// ---- kernel 3: yt[b][d][j] = bf16(x[b][j][d] / sum_ic colpart) ----
__global__ __launch_bounds__(256) void k_ytrans(const float* __restrict__ x,
                                                const float* __restrict__ colpart,
                                                unsigned short* __restrict__ yt) {
  __shared__ unsigned short T[64 * 72];
  const int b = blockIdx.z, j0 = blockIdx.y * 64, d0 = blockIdx.x * 64;
  const int tid = threadIdx.x;
  int jr = tid >> 2, q0 = (tid & 3) * 16;
  float cs = 0.f;
#pragma unroll
  for (int ic = 0; ic < 8; ++ic) cs += colpart[(ic * BN + b) * NN + j0 + jr];
  float inv = 1.0f / cs;
  const float* xr = x + (size_t)(b * NN + j0 + jr) * DD + d0 + q0;
#pragma unroll
  for (int q = 0; q < 4; ++q) {
    float4 v = *(const float4*)(xr + q * 4);
    int dc = q0 + q * 4;
    T[jr * 72 + dc + 0] = f2bf(v.x * inv);
    T[jr * 72 + dc + 1] = f2bf(v.y * inv);
    T[jr * 72 + dc + 2] = f2bf(v.z * inv);
    T[jr * 72 + dc + 3] = f2bf(v.w * inv);
  }
  __syncthreads();
  for (int c = tid; c < 512; c += 256) {
    int dr = c >> 3, jg = c & 7;
    alignas(16) unsigned short tmp[8];
#pragma unroll
    for (int u = 0; u < 8; ++u) tmp[u] = T[(jg * 8 + u) * 72 + dr];
    *(uint4*)&yt[(size_t)(b * DD + d0 + dr) * NN + j0 + jg * 8] = *(const uint4*)tmp;
  }
}

// ---- kernel 4: opart[zc][b*NN+i][:] = sum_{j in chunk zc} relu(<x_i,x_j>) y[j][:] ----
__global__ __launch_bounds__(256) void k_pass2(const unsigned short* __restrict__ xb,
                                               const unsigned short* __restrict__ yt,
                                               unsigned short* __restrict__ opart,
                                               int jspan) {
  __shared__ unsigned short Xi[64 * 128];
  __shared__ unsigned short Xj[64 * 128];  // first 8 KB reused as P after S-phase
  __shared__ unsigned short Ys[128 * 64];
  unsigned short* P = Xj;
  const int b = blockIdx.y, i0 = blockIdx.x * 64, zc = blockIdx.z;
  const int tid = threadIdx.x, lane = tid & 63, w = tid >> 6;
  const unsigned short* xbb = xb + b * NN * DD;
  const unsigned short* ytb = yt + (size_t)b * DD * NN;

  for (int c = tid; c < 1024; c += 256) {
    int row = c >> 4, g = c & 15;
    *(uint4*)&Xi[row * 128 + ((g ^ (row & 7)) << 3)] =
        *(const uint4*)&xbb[(i0 + row) * 128 + g * 8];
  }
  const int wr = w >> 1, wc = w & 1;
  f32x4 oacc[8] = {};

  const int jbeg = zc * jspan, jend = jbeg + jspan;
  for (int j0 = jbeg; j0 < jend; j0 += 64) {
    __syncthreads();  // prev PV done reading P(Xj)/Ys
    for (int c = tid; c < 2048; c += 256) {
      if (c < 1024) {
        int row = c >> 4, g = c & 15;
        *(uint4*)&Xj[row * 128 + ((g ^ (row & 7)) << 3)] =
            *(const uint4*)&xbb[(j0 + row) * 128 + g * 8];
      } else {
        int cc = c - 1024;
        int dr = cc >> 3, jg = cc & 7;
        *(uint4*)&Ys[dr * 64 + ((jg ^ (dr & 7)) << 3)] =
            *(const uint4*)&ytb[(size_t)dr * NN + j0 + jg * 8];
      }
    }
    __syncthreads();

    f32x4 acc00 = {}, acc01 = {}, acc10 = {}, acc11 = {};
#pragma unroll
    for (int kk = 0; kk < 4; ++kk) {
      int g = kk * 4 + (lane >> 4);
      bf16x8 a0, a1, b0, b1;
      { int r = wr * 32 + (lane & 15);      a0 = *(const bf16x8*)&Xi[r * 128 + ((g ^ (r & 7)) << 3)]; }
      { int r = wr * 32 + 16 + (lane & 15); a1 = *(const bf16x8*)&Xi[r * 128 + ((g ^ (r & 7)) << 3)]; }
      { int r = wc * 32 + (lane & 15);      b0 = *(const bf16x8*)&Xj[r * 128 + ((g ^ (r & 7)) << 3)]; }
      { int r = wc * 32 + 16 + (lane & 15); b1 = *(const bf16x8*)&Xj[r * 128 + ((g ^ (r & 7)) << 3)]; }
      acc00 = __builtin_amdgcn_mfma_f32_16x16x32_bf16(a0, b0, acc00, 0, 0, 0);
      acc01 = __builtin_amdgcn_mfma_f32_16x16x32_bf16(a0, b1, acc01, 0, 0, 0);
      acc10 = __builtin_amdgcn_mfma_f32_16x16x32_bf16(a1, b0, acc10, 0, 0, 0);
      acc11 = __builtin_amdgcn_mfma_f32_16x16x32_bf16(a1, b1, acc11, 0, 0, 0);
    }
    __syncthreads();  // all waves done reading Xj -> safe to overwrite with P
    // relu -> P (bf16, swizzled), exact C layout
#pragma unroll
    for (int m = 0; m < 2; ++m)
#pragma unroll
      for (int n = 0; n < 2; ++n)
#pragma unroll
        for (int r = 0; r < 4; ++r) {
          float v;
          if (m == 0 && n == 0) v = acc00[r];
          else if (m == 0 && n == 1) v = acc01[r];
          else if (m == 1 && n == 0) v = acc10[r];
          else v = acc11[r];
          int row = wr * 32 + m * 16 + (lane >> 4) * 4 + r;
          int col = wc * 32 + n * 16 + (lane & 15);
          P[row * 64 + (((col >> 3) ^ (row & 7)) << 3) + (col & 7)] = f2bf(fmaxf(v, 0.f));
        }
    __syncthreads();
    // out += P @ Y   (wave w owns rows w*16 .. w*16+15, all 128 d columns)
#pragma unroll
    for (int kq = 0; kq < 2; ++kq) {
      int g = kq * 4 + (lane >> 4);
      bf16x8 a;
      { int r = w * 16 + (lane & 15); a = *(const bf16x8*)&P[r * 64 + ((g ^ (r & 7)) << 3)]; }
#pragma unroll
      for (int n = 0; n < 8; ++n) {
        int r = n * 16 + (lane & 15);
        bf16x8 bb = *(const bf16x8*)&Ys[r * 64 + ((g ^ (r & 7)) << 3)];
        oacc[n] = __builtin_amdgcn_mfma_f32_16x16x32_bf16(a, bb, oacc[n], 0, 0, 0);
      }
    }
  }
  // epilogue: oacc (fp32) -> bf16, via LDS (Xi reused, linear) for coalesced stores
  __syncthreads();
#pragma unroll
  for (int n = 0; n < 8; ++n)
#pragma unroll
    for (int r = 0; r < 4; ++r) {
      int row = w * 16 + (lane >> 4) * 4 + r;
      int col = n * 16 + (lane & 15);
      Xi[row * 128 + col] = f2bf(oacc[n][r]);
    }
  __syncthreads();
  for (int c = tid; c < 1024; c += 256) {
    int row = c >> 4, g = c & 15;
    *(uint4*)&opart[((size_t)zc * (BN * NN) + b * NN + i0 + row) * DD + g * 8] =
        *(const uint4*)&Xi[row * 128 + g * 8];
  }
}

// ---- kernel 5: out = tanh((sum_zc opart) @ W^T + bias) + x ----
__global__ __launch_bounds__(256) void k_final(const unsigned short* __restrict__ opart,
                                               int jc,
                                               const float* __restrict__ W,
                                               const float* __restrict__ bias,
                                               const float* __restrict__ x,
                                               float* __restrict__ out) {
  __shared__ float Wt[128 * 128];          // Wt[d][h] = W[h][d]
  __shared__ unsigned short PreS[64 * 128];
  const int tid = threadIdx.x;
  const int r0 = blockIdx.x * 64;
  {
    int h = tid >> 1, k0 = (tid & 1) * 64;
    const float* wr = W + h * 128 + k0;
#pragma unroll
    for (int q = 0; q < 16; ++q) {
      float4 v = *(const float4*)(wr + q * 4);
      Wt[(k0 + q * 4 + 0) * 128 + h] = v.x;
      Wt[(k0 + q * 4 + 1) * 128 + h] = v.y;
      Wt[(k0 + q * 4 + 2) * 128 + h] = v.z;
      Wt[(k0 + q * 4 + 3) * 128 + h] = v.w;
    }
  }
  // stage row sums over jc chunks into PreS (bf16)
  for (int c = tid; c < 1024; c += 256) {
    int row = c >> 4, g = c & 15;
    float s[8] = {0.f, 0.f, 0.f, 0.f, 0.f, 0.f, 0.f, 0.f};
    for (int ch = 0; ch < jc; ++ch) {
      uint4 pk = *(const uint4*)&opart[((size_t)ch * (BN * NN) + r0 + row) * DD + g * 8];
      alignas(16) unsigned short us[8];
      *(uint4*)us = pk;
#pragma unroll
      for (int u = 0; u < 8; ++u) s[u] += bf2f(us[u]);
    }
    alignas(16) unsigned short rs[8];
#pragma unroll
    for (int u = 0; u < 8; ++u) rs[u] = f2bf(s[u]);
    *(uint4*)&PreS[row * 128 + g * 8] = *(const uint4*)rs;
  }
  const int h = tid & 127;
  float bh = bias[h];
  __syncthreads();
  for (int it = 0; it < 32; ++it) {
    int lr = it * 2 + (tid >> 7);
    int ri = r0 + lr;
    float acc = bh;
#pragma unroll
    for (int k8 = 0; k8 < 16; ++k8) {
      uint4 pk = *(const uint4*)&PreS[lr * 128 + k8 * 8];
      alignas(16) unsigned short us[8];
      *(uint4*)us = pk;
#pragma unroll
      for (int u = 0; u < 8; ++u) acc += bf2f(us[u]) * Wt[(k8 * 8 + u) * 128 + h];
    }
    out[(size_t)ri * 128 + h] = tanhf(acc) + x[(size_t)ri * 128 + h];
  }
}

extern "C" void kernel_launch(void* const* d_in, const int* in_sizes, int n_in,
                              void* d_out, int out_size, void* d_ws, size_t ws_size,
                              hipStream_t stream) {
  (void)in_sizes; (void)n_in; (void)out_size;
  const float* x = (const float*)d_in[0];
  const float* W = (const float*)d_in[1];
  const float* bias = (const float*)d_in[2];
  float* out = (float*)d_out;
  char* ws = (char*)d_ws;
  unsigned short* xb = (unsigned short*)ws;                       // 4 MB @ 0
  unsigned short* yt = (unsigned short*)(ws + (4u << 20));        // 4 MB @ 4M
  float* colpart = (float*)(ws + (8u << 20));                     // 512 KB @ 8M
  unsigned short* opart = (unsigned short*)(ws + (9u << 20));     // jc*4 MB @ 9M

  // j-chunk count for pass2: 4 if workspace allows (25 MB), else verified jc=1 path
  const size_t need4 = (9u << 20) + 4u * (4u << 20);
  const int jc = (ws_size >= need4) ? 4 : 1;

  k_cvt<<<1024, 256, 0, stream>>>(x, xb);
  k_colsum<<<dim3(64, 4, 8), 256, 0, stream>>>(xb, colpart);
  k_ytrans<<<dim3(2, 64, 4), 256, 0, stream>>>(x, colpart, yt);
  k_pass2<<<dim3(64, 4, jc), 256, 0, stream>>>(xb, yt, opart, NN / jc);
  k_final<<<256, 256, 0, stream>>>(opart, jc, W, bias, x, out);
}